// Round 1
// baseline (1449.580 us; speedup 1.0000x reference)
//
#include <hip/hip_runtime.h>
#include <math.h>

#define BATCH 512
#define TT    1024
#define FF    128
#define UU    50
#define ZN    200   // 4*UU

__device__ __forceinline__ float sigmoid_fast(float x) {
    return 1.0f / (1.0f + __expf(-x));
}
__device__ __forceinline__ float tanh_fast(float x) {
    float e = __expf(2.0f * x);
    return 1.0f - 2.0f / (e + 1.0f);
}

__launch_bounds__(256, 2)
__global__ void lstm_fused_kernel(const float* __restrict__ x,
                                  const float* __restrict__ K,
                                  const float* __restrict__ R,
                                  const float* __restrict__ bias,
                                  const float* __restrict__ dw,
                                  const float* __restrict__ db,
                                  float* __restrict__ out) {
    const int b = blockIdx.x;
    const int j = threadIdx.x;          // 0..255; j<ZN are matmul lanes

    __shared__ __align__(16) float xs[2][FF];   // double-buffered x_t
    __shared__ __align__(16) float zs[ZN];      // pre-activations
    __shared__ __align__(16) float hs[52];      // h state (padded to 52 for b128)

    // --- load weights into registers (persist across all 1024 steps) ---
    float kreg[FF];
    float rreg[52];
    float bj = 0.0f;
    if (j < ZN) {
        #pragma unroll
        for (int k = 0; k < FF; ++k) kreg[k] = K[k * ZN + j];   // coalesced over j
        #pragma unroll
        for (int k = 0; k < UU; ++k) rreg[k] = R[k * ZN + j];
        rreg[50] = 0.0f; rreg[51] = 0.0f;
        bj = bias[j];
    }
    if (j < 52) hs[j] = 0.0f;
    float c = 0.0f;                      // cell state, owned by lanes j<UU

    const float* xrow = x + (size_t)b * TT * FF;
    if (j < FF) xs[0][j] = xrow[j];
    __syncthreads();

    for (int t = 0; t < TT; ++t) {
        const int cur = t & 1, nxt = cur ^ 1;

        // prefetch next step's x_t (latency hidden under the FMA block)
        float xnext = 0.0f;
        if ((t + 1) < TT && j < FF) xnext = xrow[(size_t)(t + 1) * FF + j];

        if (j < ZN) {
            // z_j = bias_j + sum_k x_t[k]*K[k][j] + sum_k h[k]*R[k][j]
            float a0 = bj, a1 = 0.0f, a2 = 0.0f, a3 = 0.0f;
            const float4* x4 = (const float4*)xs[cur];   // uniform b128 broadcast
            #pragma unroll
            for (int kk = 0; kk < FF / 4; ++kk) {
                float4 xv = x4[kk];
                a0 = fmaf(xv.x, kreg[4 * kk + 0], a0);
                a1 = fmaf(xv.y, kreg[4 * kk + 1], a1);
                a2 = fmaf(xv.z, kreg[4 * kk + 2], a2);
                a3 = fmaf(xv.w, kreg[4 * kk + 3], a3);
            }
            const float4* h4 = (const float4*)hs;        // uniform b128 broadcast
            #pragma unroll
            for (int kk = 0; kk < 13; ++kk) {
                float4 hv = h4[kk];
                a0 = fmaf(hv.x, rreg[4 * kk + 0], a0);
                a1 = fmaf(hv.y, rreg[4 * kk + 1], a1);
                a2 = fmaf(hv.z, rreg[4 * kk + 2], a2);
                a3 = fmaf(hv.w, rreg[4 * kk + 3], a3);
            }
            zs[j] = (a0 + a1) + (a2 + a3);
        }
        __syncthreads();

        // gate combine: lane u owns unit u (i=z[u], f=z[50+u], g=z[100+u], o=z[150+u])
        if (j < UU) {
            float zi = zs[j];
            float zf = zs[j + UU];
            float zg = zs[j + 2 * UU];
            float zo = zs[j + 3 * UU];
            float fi = sigmoid_fast(zi);
            float ff = sigmoid_fast(zf);
            float fo = sigmoid_fast(zo);
            float tg = tanh_fast(zg);
            c = ff * c + fi * tg;
            hs[j] = fo * tanh_fast(c);
        }
        // stage next x into the other buffer (no conflict with xs[cur] readers)
        if ((t + 1) < TT && j < FF) xs[nxt][j] = xnext;
        __syncthreads();
    }

    // epilogue: out[b] = h_last . dense_w + dense_b  (runs once; serial is fine)
    if (j == 0) {
        float s = db[0];
        #pragma unroll
        for (int u = 0; u < UU; ++u) s = fmaf(hs[u], dw[u], s);
        out[b] = s;
    }
}

extern "C" void kernel_launch(void* const* d_in, const int* in_sizes, int n_in,
                              void* d_out, int out_size, void* d_ws, size_t ws_size,
                              hipStream_t stream) {
    const float* x    = (const float*)d_in[0];  // [512,1024,128]
    const float* K    = (const float*)d_in[1];  // [128,200]
    const float* R    = (const float*)d_in[2];  // [50,200]
    const float* bias = (const float*)d_in[3];  // [200]
    const float* dw   = (const float*)d_in[4];  // [50,1]
    const float* db   = (const float*)d_in[5];  // [1]
    float* out = (float*)d_out;                 // [512,1]

    lstm_fused_kernel<<<BATCH, 256, 0, stream>>>(x, K, R, bias, dw, db, out);
}